// Round 10
// baseline (1914.244 us; speedup 1.0000x reference)
//
#include <hip/hip_runtime.h>
#include <math.h>

#define TT 2048
#define HH 64
#define NE 16      // batch elems per block
#define NBLK 32    // 512 / NE

typedef _Float16 half8 __attribute__((ext_vector_type(8)));
typedef _Float16 half4 __attribute__((ext_vector_type(4)));
typedef float f32x4 __attribute__((ext_vector_type(4)));

__device__ __forceinline__ float sigmoid_fast(float x) {
    float e = __expf(-x);
    return __builtin_amdgcn_rcpf(1.0f + e);
}
__device__ __forceinline__ float tanh_fast(float x) {
    float e = __expf(-2.0f * x);
    return fmaf(2.0f, __builtin_amdgcn_rcpf(1.0f + e), -1.0f);
}

// MFMA LSTM, round 10: A/B rebalance via feed-in offload.
// Waves 0-3 ("A", group j): gates0(t) = Whh0.h0(t-1)+x,b  (8 MFMAs)
//   AND partial(t-1) = bias1 + Wih1.h0(t-1)               (8 MFMAs, same hf!)
//   -> partial written to LDS as f32 C-frags.
// Waves 4-7 ("B", group j): gates1(t-2) = partial(t-2) + Whh1.h1(t-3)
//   (8 MFMAs, chain depth 2, acc init from partial load).
// Rationale: only recurrent matrices are chained; Wih1.h0 is computable one
// step early by h0's producers. Round-9 imbalance (A=8 vs B=16 MFMAs + chain
// of 4) made A idle at the barrier every step.
__global__ __launch_bounds__(512, 2) __attribute__((amdgpu_waves_per_eu(2, 2)))
void lstm_mfma_kernel(const float* __restrict__ x,      // [B,T]
                      const float* __restrict__ w_ih0,  // [256,1]
                      const float* __restrict__ w_hh0,  // [256,64]
                      const float* __restrict__ b_ih0,  // [256]
                      const float* __restrict__ b_hh0,  // [256]
                      const float* __restrict__ w_ih1,  // [256,64]
                      const float* __restrict__ w_hh1,  // [256,64]
                      const float* __restrict__ b_ih1,  // [256]
                      const float* __restrict__ b_hh1,  // [256]
                      const float* __restrict__ w1, const float* __restrict__ b1,
                      const float* __restrict__ w2, const float* __restrict__ b2,
                      const float* __restrict__ w3, const float* __restrict__ b3,
                      float* __restrict__ out)          // [B,10]
{
    const int tid = threadIdx.x;
    const int w   = tid >> 6;       // wave 0..7
    const int l   = tid & 63;
    const bool isA = (w < 4);
    const int j   = w & 3;          // unit group: units [16j, 16j+16)
    const int e   = l & 15;         // elem (B-frag col / C col)
    const int kg  = l >> 4;         // k-group / C row-quad

    // h state: [layer][buf][elem*64+unit] fp16, swizzled. 8 KB.
    __shared__ __align__(16) _Float16 hL[2][2][NE * HH];
    // layer-1 feed-in partial: [buf][g][j][lane] f32x4 C-frags. 32 KB.
    __shared__ __align__(16) float pP[2][4 * 4 * 64 * 4];
    __shared__ float cls1[NE][HH];
    __shared__ float cls2[NE][32];

    // zero h buffers (partial garbage at t<2 is suppressed, but zero anyway)
    for (int i = tid; i < 2 * 2 * NE * HH; i += 512)
        ((_Float16*)hL)[i] = (_Float16)0.0f;
    for (int i = tid; i < 2 * 4 * 4 * 64 * 4; i += 512)
        ((float*)pP)[i] = 0.0f;

    // ---- weight A-frags (fp16) ----
    // A-wave: wf[0..7] = Whh0 frags [g][ks]; wf[8..15] = Wih1 frags.
    // B-wave: wf[0..7] = Whh1 frags;        wf[8..15] zero.
    half8 wf[16];
    float bv[16], bp[16], wx[16];
    {
        const float* W0 = isA ? w_hh0 : w_hh1;
        #pragma unroll
        for (int g = 0; g < 4; ++g) {
            const int row = g * 64 + 16 * j + (l & 15);   // A-frag row = l&15
            #pragma unroll
            for (int ks = 0; ks < 2; ++ks) {
                const int c0 = ks * 32 + 8 * kg;
                half8 v;
                #pragma unroll
                for (int i = 0; i < 8; ++i) v[i] = (_Float16)W0[row * HH + c0 + i];
                wf[g * 2 + ks] = v;
            }
        }
        if (isA) {
            #pragma unroll
            for (int g = 0; g < 4; ++g) {
                const int row = g * 64 + 16 * j + (l & 15);
                #pragma unroll
                for (int ks = 0; ks < 2; ++ks) {
                    const int c0 = ks * 32 + 8 * kg;
                    half8 v;
                    #pragma unroll
                    for (int i = 0; i < 8; ++i) v[i] = (_Float16)w_ih1[row * HH + c0 + i];
                    wf[8 + g * 2 + ks] = v;
                }
            }
        } else {
            #pragma unroll
            for (int f = 8; f < 16; ++f) {
                half8 v;
                #pragma unroll
                for (int i = 0; i < 8; ++i) v[i] = (_Float16)0.0f;
                wf[f] = v;
            }
        }
        // per-(g,r) scalars: C row = g*64 + 16j + 4*kg + r
        #pragma unroll
        for (int g = 0; g < 4; ++g) {
            #pragma unroll
            for (int r = 0; r < 4; ++r) {
                const int row = g * 64 + 16 * j + 4 * kg + r;
                bv[g * 4 + r] = isA ? (b_ih0[row] + b_hh0[row]) : 0.0f;
                bp[g * 4 + r] = isA ? (b_ih1[row] + b_hh1[row]) : 0.0f;
                wx[g * 4 + r] = isA ? w_ih0[row] : 0.0f;
            }
        }
    }
    // pin (rounds 1-4 lesson: allocator rematerializes weight loads otherwise)
    #pragma unroll
    for (int i = 0; i < 16; ++i) {
        asm volatile("" : "+v"(wf[i]));
        asm volatile("" : "+v"(bv[i]));
        asm volatile("" : "+v"(bp[i]));
        asm volatile("" : "+v"(wx[i]));
    }

    // per-lane x (elem e), prefetched one step ahead
    const float* xg = x + (size_t)(blockIdx.x * NE + e) * TT;
    float xc = xg[0];

    float cst[4] = {0.0f, 0.0f, 0.0f, 0.0f};   // c-state: 4 units, elem e
    __syncthreads();

    const int swz = (e & 7) << 4;
    char* const hb00 = (char*)&hL[0][0][0];
    char* const hb01 = (char*)&hL[0][1][0];
    char* const hb10 = (char*)&hL[1][0][0];
    char* const hb11 = (char*)&hL[1][1][0];
    // partial slot for this lane: (g, j, kg, e) -> ((g*4 + j)*64 + l) * 16B
    const int pOff = (j << 10) + (l << 4);      // + g*4096 bytes

    for (int t = 0; t <= TT + 1; ++t) {
        const int wb = t & 1;
        float xn = xg[(t + 1 < TT) ? (t + 1) : (TT - 1)];   // prefetch

        const char* h0r = wb ? hb00 : hb01;   // read buf = wb^1
        const char* h1r = wb ? hb10 : hb11;
        char* pW = (char*)&pP[wb][0];          // write partial buf = wb
        const char* pR = (char*)&pP[wb ^ 1][0];

        f32x4 acc[4];
        half4 hv;

        if (isA) {
            half8 hf0 = *(const half8*)(h0r + e * 128 + ((kg * 16) ^ swz));
            half8 hf1 = *(const half8*)(h0r + e * 128 + ((64 + kg * 16) ^ swz));
            f32x4 pac[4];
            #pragma unroll
            for (int g = 0; g < 4; ++g) {
                #pragma unroll
                for (int r = 0; r < 4; ++r) {
                    acc[g][r] = fmaf(wx[g * 4 + r], xc, bv[g * 4 + r]);
                    pac[g][r] = bp[g * 4 + r];
                }
            }
            #pragma unroll
            for (int g = 0; g < 4; ++g) {
                acc[g] = __builtin_amdgcn_mfma_f32_16x16x32_f16(wf[g * 2 + 0], hf0, acc[g], 0, 0, 0);
                acc[g] = __builtin_amdgcn_mfma_f32_16x16x32_f16(wf[g * 2 + 1], hf1, acc[g], 0, 0, 0);
                pac[g] = __builtin_amdgcn_mfma_f32_16x16x32_f16(wf[8 + g * 2 + 0], hf0, pac[g], 0, 0, 0);
                pac[g] = __builtin_amdgcn_mfma_f32_16x16x32_f16(wf[8 + g * 2 + 1], hf1, pac[g], 0, 0, 0);
            }
            // publish feed-in partial(t-1) for B at step t+1
            #pragma unroll
            for (int g = 0; g < 4; ++g)
                *(f32x4*)(pW + (g << 12) + pOff) = pac[g];
        } else {
            half8 hf2 = *(const half8*)(h1r + e * 128 + ((kg * 16) ^ swz));
            half8 hf3 = *(const half8*)(h1r + e * 128 + ((64 + kg * 16) ^ swz));
            #pragma unroll
            for (int g = 0; g < 4; ++g)
                acc[g] = *(const f32x4*)(pR + (g << 12) + pOff);
            #pragma unroll
            for (int g = 0; g < 4; ++g) {
                acc[g] = __builtin_amdgcn_mfma_f32_16x16x32_f16(wf[g * 2 + 0], hf2, acc[g], 0, 0, 0);
                acc[g] = __builtin_amdgcn_mfma_f32_16x16x32_f16(wf[g * 2 + 1], hf3, acc[g], 0, 0, 0);
            }
        }

        // activations + state update (lane-local: 4 units x elem e)
        #pragma unroll
        for (int r = 0; r < 4; ++r) {
            float gi = sigmoid_fast(acc[0][r]);
            float gf = sigmoid_fast(acc[1][r]);
            float gg = tanh_fast(acc[2][r]);
            float go = sigmoid_fast(acc[3][r]);
            float c  = fmaf(gf, cst[r], gi * gg);
            float h  = go * tanh_fast(c);
            if (!isA && t <= 1) { c = 0.0f; h = 0.0f; }   // h1(s<0) = 0
            cst[r] = c;
            hv[r]  = (_Float16)h;
        }

        // write h (4 contiguous units, 8B, swizzled)
        {
            char* hwv = isA ? (wb ? hb01 : hb00) : (wb ? hb11 : hb10);
            const int u0 = 16 * j + 4 * kg;
            *(half4*)(hwv + e * 128 + ((u0 * 2) ^ swz)) = hv;
        }
        xc = xn;
        __syncthreads();
    }

    // ---- classifier head; h_last = h1(TT-1) written at t=TT+1 -> buf 1 ----
    const char* h1f = hb11;
    #pragma unroll
    for (int p = 0; p < 2; ++p) {
        const int ee = w + 8 * p;
        const int esw = (ee & 7) << 4;
        float a = b1[l];
        #pragma unroll 8
        for (int k = 0; k < HH; ++k) {
            _Float16 hk = *(const _Float16*)(h1f + ee * 128 + ((k * 2) ^ esw));
            a = fmaf(w1[l * HH + k], (float)hk, a);
        }
        cls1[ee][l] = fmaxf(a, 0.0f);
        __syncthreads();
        if (l < 32) {
            float a2 = b2[l];
            #pragma unroll 8
            for (int k = 0; k < HH; ++k) a2 = fmaf(w2[l * HH + k], cls1[ee][k], a2);
            cls2[ee][l] = fmaxf(a2, 0.0f);
        }
        __syncthreads();
        if (l < 10) {
            float a3 = b3[l];
            #pragma unroll
            for (int k = 0; k < 32; ++k) a3 = fmaf(w3[l * 32 + k], cls2[ee][k], a3);
            out[(blockIdx.x * NE + ee) * 10 + l] = a3;
        }
        __syncthreads();
    }
}

extern "C" void kernel_launch(void* const* d_in, const int* in_sizes, int n_in,
                              void* d_out, int out_size, void* d_ws, size_t ws_size,
                              hipStream_t stream) {
    const float* x     = (const float*)d_in[0];
    const float* w_ih0 = (const float*)d_in[1];
    const float* w_hh0 = (const float*)d_in[2];
    const float* b_ih0 = (const float*)d_in[3];
    const float* b_hh0 = (const float*)d_in[4];
    const float* w_ih1 = (const float*)d_in[5];
    const float* w_hh1 = (const float*)d_in[6];
    const float* b_ih1 = (const float*)d_in[7];
    const float* b_hh1 = (const float*)d_in[8];
    const float* w1    = (const float*)d_in[9];
    const float* b1    = (const float*)d_in[10];
    const float* w2    = (const float*)d_in[11];
    const float* b2    = (const float*)d_in[12];
    const float* w3    = (const float*)d_in[13];
    const float* b3    = (const float*)d_in[14];
    float* out = (float*)d_out;

    lstm_mfma_kernel<<<NBLK, 512, 0, stream>>>(x, w_ih0, w_hh0, b_ih0, b_hh0,
                                               w_ih1, w_hh1, b_ih1, b_hh1,
                                               w1, b1, w2, b2, w3, b3, out);
}

// Round 11
// 1247.739 us; speedup vs baseline: 1.5342x; 1.5342x over previous
//
#include <hip/hip_runtime.h>
#include <math.h>

#define TT 2048
#define HH 64
#define NE 4       // batch elems per block
#define NBLK 128   // 512 / NE

typedef _Float16 half8 __attribute__((ext_vector_type(8)));
typedef float f32x4 __attribute__((ext_vector_type(4)));

__device__ __forceinline__ float sigmoid_fast(float x) {
    float e = __expf(-x);
    return __builtin_amdgcn_rcpf(1.0f + e);
}
__device__ __forceinline__ float tanh_fast(float x) {
    float e = __expf(-2.0f * x);
    return fmaf(2.0f, __builtin_amdgcn_rcpf(1.0f + e), -1.0f);
}

// Round 11: 2-phase MFMA LSTM, NE=4 elems/block, 128 blocks (4x more CUs).
// Round-9/10 decode: per-CU step cost = trans pipe ~640cy (4 unit-elems/lane
// forced by C-frag gate-locality) + MFMA pipe ~456cy; only 32 CUs active.
// Fix: redistribute gates through LDS so activation lanes are fully packed
// (1 unit-elem/lane -> 10 trans insts), and spread batch over 128 blocks.
// Phase 1: 8 waves x 12 MFMAs (48 tile-matrix jobs), raw gates -> glds.
// Phase 2: lane = (layer,unit,elem): +bias/+x, sigmoid/tanh, c/h update,
// h -> fp16 swizzled LDS. Two barriers/step; single-buffered h (barrier
// orders read-before-overwrite). Skew: gates1(t-1) computed at step t.
__global__ __launch_bounds__(512, 2) __attribute__((amdgpu_waves_per_eu(2, 2)))
void lstm_mfma2_kernel(const float* __restrict__ x,      // [B,T]
                       const float* __restrict__ w_ih0,  // [256,1]
                       const float* __restrict__ w_hh0,  // [256,64]
                       const float* __restrict__ b_ih0,  // [256]
                       const float* __restrict__ b_hh0,  // [256]
                       const float* __restrict__ w_ih1,  // [256,64]
                       const float* __restrict__ w_hh1,  // [256,64]
                       const float* __restrict__ b_ih1,  // [256]
                       const float* __restrict__ b_hh1,  // [256]
                       const float* __restrict__ w1, const float* __restrict__ b1,
                       const float* __restrict__ w2, const float* __restrict__ b2,
                       const float* __restrict__ w3, const float* __restrict__ b3,
                       float* __restrict__ out)          // [B,10]
{
    const int tid = threadIdx.x;
    const int wv  = tid >> 6;        // wave 0..7
    const int l   = tid & 63;
    const int e16 = l & 15;          // MFMA col (elem; valid < NE)
    const int kg  = l >> 4;          // k-group / C row-quad
    const int bA  = blockIdx.x * NE;

    __shared__ __align__(16) float xs[(TT + 1) * (NE + 1)];    // [t][5] pad
    __shared__ __align__(16) float glds[2][4][NE][72];         // [L][g][e][u pad]
    __shared__ __align__(16) _Float16 h0lds[16 * 64];          // [e16][u] swizzled
    __shared__ __align__(16) _Float16 h1lds[16 * 64];
    __shared__ float cls1[NE][HH];
    __shared__ float cls2[NE][32];

    // zero h (rows 4..15 are garbage cols, still readable)
    for (int i = tid; i < 16 * 64; i += 512) {
        h0lds[i] = (_Float16)0.0f;
        h1lds[i] = (_Float16)0.0f;
    }
    // stage x: xs[t*5+e] (stride-5 -> conflict-free), coalesced global reads
    for (int i = tid; i < NE * TT; i += 512) {
        const int e = i >> 11, t = i & (TT - 1);
        xs[t * (NE + 1) + e] = x[(size_t)(bA + e) * TT + t];
    }
    if (tid < NE + 1) xs[TT * (NE + 1) + tid] = 0.0f;   // pad row t=TT

    // ---- weight A-frags (fp16): 12 half8 = 48 VGPR per lane ----
    // waves 0-3: wf[0..7]=Whh0 (g=0..3, tj=wv); wf[8..9]=Wih1, wf[10..11]=Whh1 (job q=wv: g=0,tj=wv)
    // waves 4-7: 3 layer-1 jobs q=4+(wv-4)*3+m: wf[m*4+{0,1}]=Wih1, wf[m*4+{2,3}]=Whh1
    half8 wf[12];
    {
        auto frag = [&](const float* M, int row, int kc) {
            half8 v;
            #pragma unroll
            for (int i = 0; i < 8; ++i) v[i] = (_Float16)M[row * HH + kc * 32 + kg * 8 + i];
            return v;
        };
        if (wv < 4) {
            #pragma unroll
            for (int g = 0; g < 4; ++g)
                #pragma unroll
                for (int kc = 0; kc < 2; ++kc)
                    wf[g * 2 + kc] = frag(w_hh0, g * 64 + 16 * wv + e16, kc);
            #pragma unroll
            for (int kc = 0; kc < 2; ++kc) {
                wf[8 + kc]  = frag(w_ih1, 16 * wv + e16, kc);
                wf[10 + kc] = frag(w_hh1, 16 * wv + e16, kc);
            }
        } else {
            const int qb = 4 + (wv - 4) * 3;
            #pragma unroll
            for (int m = 0; m < 3; ++m) {
                const int q = qb + m, g = q >> 2, tj = q & 3;
                #pragma unroll
                for (int kc = 0; kc < 2; ++kc) {
                    wf[m * 4 + kc]     = frag(w_ih1, g * 64 + 16 * tj + e16, kc);
                    wf[m * 4 + 2 + kc] = frag(w_hh1, g * 64 + 16 * tj + e16, kc);
                }
            }
        }
    }

    // ---- activation-phase identity: lane owns (L, unit au, elem ae) ----
    const int L  = tid >> 8;         // 0: layer0 (waves 0-3), 1: layer1
    const int au = (tid >> 2) & 63;
    const int ae = tid & 3;
    float bi[4], wxr[4];
    {
        const float* bihp = L ? b_ih1 : b_ih0;
        const float* bhhp = L ? b_hh1 : b_hh0;
        #pragma unroll
        for (int g = 0; g < 4; ++g) {
            bi[g]  = bihp[g * 64 + au] + bhhp[g * 64 + au];
            wxr[g] = L ? 0.0f : w_ih0[g * 64 + au];
        }
    }
    // pin (rounds 1-4 lesson: allocator rematerializes weight loads otherwise)
    #pragma unroll
    for (int i = 0; i < 12; ++i) asm volatile("" : "+v"(wf[i]));
    #pragma unroll
    for (int g = 0; g < 4; ++g) {
        asm volatile("" : "+v"(bi[g]));
        asm volatile("" : "+v"(wxr[g]));
    }

    float c = 0.0f;                                   // lane's cell state
    _Float16* const hW = L ? h1lds : h0lds;           // act write target
    const int hwb = ae * 128 + ((2 * au) ^ (ae << 4));   // byte, swizzled

    const int swz16 = (e16 & 7) << 4;
    const int hro0 = e16 * 128 + ((16 * kg) ^ swz16);        // k-chunk 0
    const int hro1 = e16 * 128 + ((64 + 16 * kg) ^ swz16);   // k-chunk 1
    const f32x4 z4 = {0.0f, 0.0f, 0.0f, 0.0f};

    __syncthreads();

    for (int t = 0; t <= TT; ++t) {
        // ---- phase 1: MFMA gates0(t), gates1(t-1) -> glds (raw, no bias) ----
        half8 h0f0 = *(const half8*)((const char*)h0lds + hro0);
        half8 h0f1 = *(const half8*)((const char*)h0lds + hro1);
        half8 h1f0 = *(const half8*)((const char*)h1lds + hro0);
        half8 h1f1 = *(const half8*)((const char*)h1lds + hro1);
        if (wv < 4) {
            f32x4 a[4], pa;
            #pragma unroll
            for (int g = 0; g < 4; ++g) {
                a[g] = __builtin_amdgcn_mfma_f32_16x16x32_f16(wf[g * 2 + 0], h0f0, z4, 0, 0, 0);
                a[g] = __builtin_amdgcn_mfma_f32_16x16x32_f16(wf[g * 2 + 1], h0f1, a[g], 0, 0, 0);
            }
            pa = __builtin_amdgcn_mfma_f32_16x16x32_f16(wf[8],  h0f0, z4, 0, 0, 0);
            pa = __builtin_amdgcn_mfma_f32_16x16x32_f16(wf[9],  h0f1, pa, 0, 0, 0);
            pa = __builtin_amdgcn_mfma_f32_16x16x32_f16(wf[10], h1f0, pa, 0, 0, 0);
            pa = __builtin_amdgcn_mfma_f32_16x16x32_f16(wf[11], h1f1, pa, 0, 0, 0);
            if (e16 < NE) {
                const int u0 = 16 * wv + 4 * kg;
                #pragma unroll
                for (int g = 0; g < 4; ++g)
                    *(f32x4*)&glds[0][g][e16][u0] = a[g];
                *(f32x4*)&glds[1][0][e16][u0] = pa;    // job q=wv: g=0, tj=wv
            }
        } else {
            f32x4 p[3];
            const int qb = 4 + (wv - 4) * 3;
            #pragma unroll
            for (int m = 0; m < 3; ++m) {
                p[m] = __builtin_amdgcn_mfma_f32_16x16x32_f16(wf[m * 4 + 0], h0f0, z4, 0, 0, 0);
                p[m] = __builtin_amdgcn_mfma_f32_16x16x32_f16(wf[m * 4 + 1], h0f1, p[m], 0, 0, 0);
                p[m] = __builtin_amdgcn_mfma_f32_16x16x32_f16(wf[m * 4 + 2], h1f0, p[m], 0, 0, 0);
                p[m] = __builtin_amdgcn_mfma_f32_16x16x32_f16(wf[m * 4 + 3], h1f1, p[m], 0, 0, 0);
            }
            if (e16 < NE) {
                #pragma unroll
                for (int m = 0; m < 3; ++m) {
                    const int q = qb + m;
                    *(f32x4*)&glds[1][q >> 2][e16][16 * (q & 3) + 4 * kg] = p[m];
                }
            }
        }
        __syncthreads();

        // ---- phase 2: activation, 1 unit-elem per lane (10 trans) ----
        {
            float z0 = glds[L][0][ae][au];
            float z1 = glds[L][1][ae][au];
            float z2 = glds[L][2][ae][au];
            float z3 = glds[L][3][ae][au];
            const float xt = xs[t * (NE + 1) + ae];
            z0 += fmaf(wxr[0], xt, bi[0]);
            z1 += fmaf(wxr[1], xt, bi[1]);
            z2 += fmaf(wxr[2], xt, bi[2]);
            z3 += fmaf(wxr[3], xt, bi[3]);
            float gi = sigmoid_fast(z0);
            float gf = sigmoid_fast(z1);
            float gg = tanh_fast(z2);
            float go = sigmoid_fast(z3);
            c = fmaf(gf, c, gi * gg);
            float h = go * tanh_fast(c);
            if (L && t == 0) { c = 0.0f; h = 0.0f; }   // enforce h1(-1)=0
            *(_Float16*)((char*)hW + hwb) = (_Float16)h;
        }
        __syncthreads();
    }
    // h1lds now holds h1(TT-1) = h_last

    // ---- classifier head: wave wv<4 handles elem wv ----
    if (wv < 4) {
        float a = b1[l];
        #pragma unroll 8
        for (int k = 0; k < HH; ++k) {
            const float hk = (float)*(const _Float16*)((const char*)h1lds
                                + wv * 128 + ((2 * k) ^ (wv << 4)));
            a = fmaf(w1[l * HH + k], hk, a);
        }
        cls1[wv][l] = fmaxf(a, 0.0f);
    }
    __syncthreads();
    if (wv < 4 && l < 32) {
        float a = b2[l];
        #pragma unroll 8
        for (int k = 0; k < HH; ++k) a = fmaf(w2[l * HH + k], cls1[wv][k], a);
        cls2[wv][l] = fmaxf(a, 0.0f);
    }
    __syncthreads();
    if (wv < 4 && l < 10) {
        float a = b3[l];
        #pragma unroll
        for (int k = 0; k < 32; ++k) a = fmaf(w3[l * 32 + k], cls2[wv][k], a);
        out[(size_t)(bA + wv) * 10 + l] = a;
    }
}

extern "C" void kernel_launch(void* const* d_in, const int* in_sizes, int n_in,
                              void* d_out, int out_size, void* d_ws, size_t ws_size,
                              hipStream_t stream) {
    const float* x     = (const float*)d_in[0];
    const float* w_ih0 = (const float*)d_in[1];
    const float* w_hh0 = (const float*)d_in[2];
    const float* b_ih0 = (const float*)d_in[3];
    const float* b_hh0 = (const float*)d_in[4];
    const float* w_ih1 = (const float*)d_in[5];
    const float* w_hh1 = (const float*)d_in[6];
    const float* b_ih1 = (const float*)d_in[7];
    const float* b_hh1 = (const float*)d_in[8];
    const float* w1    = (const float*)d_in[9];
    const float* b1    = (const float*)d_in[10];
    const float* w2    = (const float*)d_in[11];
    const float* b2    = (const float*)d_in[12];
    const float* w3    = (const float*)d_in[13];
    const float* b3    = (const float*)d_in[14];
    float* out = (float*)d_out;

    lstm_mfma2_kernel<<<NBLK, 512, 0, stream>>>(x, w_ih0, w_hh0, b_ih0, b_hh0,
                                                w_ih1, w_hh1, b_ih1, b_hh1,
                                                w1, b1, w2, b2, w3, b3, out);
}